// Round 8
// baseline (4486.461 us; speedup 1.0000x reference)
//
#include <hip/hip_runtime.h>
#include <math.h>

#define N_NODES 50000
#define N_EDGES 800000
#define TPB 256

// ---------------- register-blocked f32 GEMM, double-buffered staging ----------------
// out[M,NO] = act( [A1 | A2] @ [W1 ; W2] + bias ),  K = K1 + K2
// BM=128, BN=64, BK=32, 256 threads, 8x4 micro-tile.
// Pipeline: issue tile t+1 global->regs, compute tile t from LDS, barrier,
// regs->LDS, barrier. Global latency hides under the 2048-cyc FMA phase.
// sA reads (2x b128, 16 unique addrs over 64 floats): 2-way bank alias = free.
// sB reads (1x b128, 4 unique addrs/wave): broadcast, conflict-free.
template<int ACT>
__global__ __launch_bounds__(256, 4) void gemm_f32(
    const float* __restrict__ A1, int K1, const float* __restrict__ A2, int K2,
    const float* __restrict__ W1, const float* __restrict__ W2,
    const float* __restrict__ bias, float* __restrict__ out, int NO) {
    constexpr int BM = 128, BN = 64, BK = 32;
    __shared__ float sA[BK][BM + 4];
    __shared__ float sB[BK][BN + 4];
    const int K = K1 + K2;
    const int T = (K + BK - 1) / BK;
    const int tid = threadIdx.x;
    const int tm = tid & 15, tn = tid >> 4;      // 16 x 16 thread grid
    const int row0 = blockIdx.y * BM;
    const int col0 = blockIdx.x * BN;
    float regA[16], regB[8];
    float acc[8][4] = {};

#define LOAD_TILE(t)                                                          \
    {                                                                         \
        _Pragma("unroll")                                                     \
        for (int j = 0; j < 16; ++j) {                                        \
            int e = tid + j * 256;                                            \
            int kk = e & 31, m = e >> 5;                                      \
            int kg = (t) * BK + kk, mg = row0 + m;                            \
            float v = 0.f;                                                    \
            if (mg < N_NODES) {                                               \
                if (kg < K1) v = A1[(size_t)mg * K1 + kg];                    \
                else if (kg < K) v = A2[(size_t)mg * K2 + (kg - K1)];         \
            }                                                                 \
            regA[j] = v;                                                      \
        }                                                                     \
        _Pragma("unroll")                                                     \
        for (int j = 0; j < 8; ++j) {                                         \
            int e = tid + j * 256;                                            \
            int n = e & 63, kk = e >> 6;                                      \
            int kg = (t) * BK + kk, ng = col0 + n;                            \
            float v = 0.f;                                                    \
            if (kg < K1) v = W1[(size_t)kg * NO + ng];                        \
            else if (kg < K) v = W2[(size_t)(kg - K1) * NO + ng];             \
            regB[j] = v;                                                      \
        }                                                                     \
    }

#define STORE_TILE()                                                          \
    {                                                                         \
        _Pragma("unroll")                                                     \
        for (int j = 0; j < 16; ++j) {                                        \
            int e = tid + j * 256;                                            \
            sA[e & 31][e >> 5] = regA[j];                                     \
        }                                                                     \
        _Pragma("unroll")                                                     \
        for (int j = 0; j < 8; ++j) {                                         \
            int e = tid + j * 256;                                            \
            sB[e >> 6][e & 63] = regB[j];                                     \
        }                                                                     \
    }

    LOAD_TILE(0);
    STORE_TILE();
    __syncthreads();

    for (int t = 0; t < T; ++t) {
        if (t + 1 < T) LOAD_TILE(t + 1);   // in flight during compute
#pragma unroll
        for (int kk = 0; kk < BK; ++kk) {
            float4 a0 = *(const float4*)&sA[kk][tm * 4];
            float4 a1 = *(const float4*)&sA[kk][64 + tm * 4];
            float4 b0 = *(const float4*)&sB[kk][tn * 4];
            float a[8] = {a0.x, a0.y, a0.z, a0.w, a1.x, a1.y, a1.z, a1.w};
            float b[4] = {b0.x, b0.y, b0.z, b0.w};
#pragma unroll
            for (int i = 0; i < 8; ++i)
#pragma unroll
                for (int j2 = 0; j2 < 4; ++j2)
                    acc[i][j2] = fmaf(a[i], b[j2], acc[i][j2]);
        }
        __syncthreads();
        if (t + 1 < T) {
            STORE_TILE();                  // vmcnt wait lands here
            __syncthreads();
        }
    }

    const int ng = col0 + tn * 4;
    float4 bb = {0.f, 0.f, 0.f, 0.f};
    if (bias) bb = *(const float4*)&bias[ng];
#pragma unroll
    for (int i = 0; i < 8; ++i) {
        int mg = row0 + ((i < 4) ? (tm * 4 + i) : (64 + tm * 4 + (i - 4)));
        if (mg >= N_NODES) continue;
        float4 v;
        v.x = acc[i][0] + bb.x;
        v.y = acc[i][1] + bb.y;
        v.z = acc[i][2] + bb.z;
        v.w = acc[i][3] + bb.w;
        if (ACT) {
            v.x = fmaxf(v.x, 0.f); v.y = fmaxf(v.y, 0.f);
            v.z = fmaxf(v.z, 0.f); v.w = fmaxf(v.w, 0.f);
        }
        *(float4*)&out[(size_t)mg * NO + ng] = v;
    }
#undef LOAD_TILE
#undef STORE_TILE
}

// ---------------- CSR construction ----------------
__global__ void hist_k(const int* __restrict__ dst, int* __restrict__ deg) {
    int e = blockIdx.x * TPB + threadIdx.x;
    if (e < N_EDGES) atomicAdd(&deg[dst[e]], 1);
}

// single-block exclusive scan over deg -> rowptr (N_NODES+1 entries)
__global__ void scan_k(const int* __restrict__ deg, int* __restrict__ rowptr) {
    __shared__ int part[1024];
    const int tid = threadIdx.x;                     // 1024 threads
    const int CH = (N_NODES + 1023) / 1024;          // 49
    const int base = tid * CH;
    int s = 0;
    for (int i = 0; i < CH; ++i) {
        int idx = base + i;
        if (idx < N_NODES) s += deg[idx];
    }
    part[tid] = s;
    __syncthreads();
    for (int off = 1; off < 1024; off <<= 1) {
        int v = (tid >= off) ? part[tid - off] : 0;
        __syncthreads();
        part[tid] += v;
        __syncthreads();
    }
    int run = (tid == 0) ? 0 : part[tid - 1];
    for (int i = 0; i < CH; ++i) {
        int idx = base + i;
        if (idx < N_NODES) {
            rowptr[idx] = run;
            run += deg[idx];
        }
    }
    if (tid == 1023) rowptr[N_NODES] = run;
}

__global__ void fill_k(const int* __restrict__ src, const int* __restrict__ dst,
                       const int* __restrict__ rowptr, int* __restrict__ fill,
                       int* __restrict__ csr_src) {
    int e = blockIdx.x * TPB + threadIdx.x;
    if (e >= N_EDGES) return;
    int d = dst[e];
    int pos = rowptr[d] + atomicAdd(&fill[d], 1);
    csr_src[pos] = src[e];
}

// ---------------- gather aggregations (no scatter atomics) ----------------
// scalar version (small F, SAGE1's F=20)
template<int F, int BLK>
__global__ void gather_mean(const int* __restrict__ rowptr, const int* __restrict__ csr_src,
                            const float* __restrict__ feat, float* __restrict__ out) {
    int n = blockIdx.x;
    int c = threadIdx.x;
    if (c >= F) return;
    int e0 = rowptr[n], e1 = rowptr[n + 1];
    float acc = 0.f;
    for (int e = e0; e < e1; ++e)
        acc += feat[(size_t)csr_src[e] * F + c];
    out[(size_t)n * F + c] = acc / fmaxf((float)(e1 - e0), 1.0f);
}

// float4 version for F=128: 32 lanes/node, 8 nodes per 256-thread block
__global__ void gather_mean4(const int* __restrict__ rowptr, const int* __restrict__ csr_src,
                             const float4* __restrict__ feat4, float4* __restrict__ out4) {
    int tid = threadIdx.x;
    int n = blockIdx.x * 8 + (tid >> 5);
    int c = tid & 31;
    int e0 = rowptr[n], e1 = rowptr[n + 1];
    float4 acc = {0.f, 0.f, 0.f, 0.f};
    for (int e = e0; e < e1; ++e) {
        float4 v = feat4[(size_t)csr_src[e] * 32 + c];
        acc.x += v.x; acc.y += v.y; acc.z += v.z; acc.w += v.w;
    }
    float inv = 1.0f / fmaxf((float)(e1 - e0), 1.0f);
    acc.x *= inv; acc.y *= inv; acc.z *= inv; acc.w *= inv;
    out4[(size_t)n * 32 + c] = acc;
}

// per-(node,head) attention scores
__global__ void att_scores(const float* __restrict__ h, const float* __restrict__ att_src,
                           const float* __restrict__ att_dst, float* __restrict__ as_,
                           float* __restrict__ ad_) {
    int idx = blockIdx.x * TPB + threadIdx.x;
    if (idx >= N_NODES * 4) return;
    int n = idx >> 2, hd = idx & 3;
    const float* row = h + (size_t)n * 128 + hd * 32;
    float sa = 0.f, sd = 0.f;
    for (int c = 0; c < 32; ++c) {
        float v = row[c];
        sa = fmaf(v, att_src[hd * 32 + c], sa);
        sd = fmaf(v, att_dst[hd * 32 + c], sd);
    }
    as_[idx] = sa;
    ad_[idx] = sd;
}

// fused GAT aggregation, float4: online softmax + weighted gather + ELU
// 32 lanes/node (4 heads x 8 float4-lanes), 8 nodes per 256-thread block
__global__ void gat_gather4(const int* __restrict__ rowptr, const int* __restrict__ csr_src,
                            const float4* __restrict__ h4, const float* __restrict__ as_,
                            const float* __restrict__ ad_, const float* __restrict__ gb,
                            float4* __restrict__ out4) {
    int tid = threadIdx.x;
    int n = blockIdx.x * 8 + (tid >> 5);
    int c = tid & 31;              // float4 index within row; head = c>>3
    int hd = c >> 3;
    int e0 = rowptr[n], e1 = rowptr[n + 1];
    float ad = ad_[n * 4 + hd];
    float m = -INFINITY, s = 0.f;
    float4 acc = {0.f, 0.f, 0.f, 0.f};
    for (int e = e0; e < e1; ++e) {
        int sn = csr_src[e];
        float a = as_[sn * 4 + hd] + ad;
        a = a >= 0.f ? a : 0.2f * a;              // leaky_relu 0.2
        if (a > m) {                               // online softmax rescale
            float sc = __expf(m - a);
            s *= sc; acc.x *= sc; acc.y *= sc; acc.z *= sc; acc.w *= sc;
            m = a;
        }
        float ex = __expf(a - m);
        s += ex;
        float4 v = h4[(size_t)sn * 32 + c];
        acc.x = fmaf(v.x, ex, acc.x); acc.y = fmaf(v.y, ex, acc.y);
        acc.z = fmaf(v.z, ex, acc.z); acc.w = fmaf(v.w, ex, acc.w);
    }
    float inv = 1.0f / (s + 1e-16f);
    float4 r;
    r.x = acc.x * inv + gb[c * 4 + 0];
    r.y = acc.y * inv + gb[c * 4 + 1];
    r.z = acc.z * inv + gb[c * 4 + 2];
    r.w = acc.w * inv + gb[c * 4 + 3];
    r.x = r.x > 0.f ? r.x : expm1f(r.x);
    r.y = r.y > 0.f ? r.y : expm1f(r.y);
    r.z = r.z > 0.f ? r.z : expm1f(r.z);
    r.w = r.w > 0.f ? r.w : expm1f(r.w);
    out4[(size_t)n * 32 + c] = r;
}

// classifier: [N,256] @ [256,5] + b
__global__ void cls_k(const float* __restrict__ h, const float* __restrict__ W,
                      const float* __restrict__ b, float* __restrict__ out) {
    __shared__ float sW[256 * 5];
    for (int i = threadIdx.x; i < 1280; i += TPB) sW[i] = W[i];
    __syncthreads();
    int n = blockIdx.x * TPB + threadIdx.x;
    if (n >= N_NODES) return;
    const float4* row = (const float4*)(h + (size_t)n * 256);
    float acc[5] = {0.f, 0.f, 0.f, 0.f, 0.f};
    for (int k4 = 0; k4 < 64; ++k4) {
        float4 v = row[k4];
        const float* w = &sW[k4 * 4 * 5];
#pragma unroll
        for (int c = 0; c < 5; ++c) acc[c] = fmaf(v.x, w[c], acc[c]);
#pragma unroll
        for (int c = 0; c < 5; ++c) acc[c] = fmaf(v.y, w[5 + c], acc[c]);
#pragma unroll
        for (int c = 0; c < 5; ++c) acc[c] = fmaf(v.z, w[10 + c], acc[c]);
#pragma unroll
        for (int c = 0; c < 5; ++c) acc[c] = fmaf(v.w, w[15 + c], acc[c]);
    }
#pragma unroll
    for (int c = 0; c < 5; ++c) out[(size_t)n * 5 + c] = acc[c] + b[c];
}

extern "C" void kernel_launch(void* const* d_in, const int* in_sizes, int n_in,
                              void* d_out, int out_size, void* d_ws, size_t ws_size,
                              hipStream_t stream) {
    const float* x    = (const float*)d_in[0];
    const int*   ei   = (const int*)d_in[1];
    const float* s1Wl = (const float*)d_in[2];
    const float* s1Wr = (const float*)d_in[3];
    const float* s1b  = (const float*)d_in[4];
    const float* gW   = (const float*)d_in[5];
    const float* gas  = (const float*)d_in[6];
    const float* gad  = (const float*)d_in[7];
    const float* gb   = (const float*)d_in[8];
    const float* s2Wl = (const float*)d_in[9];
    const float* s2Wr = (const float*)d_in[10];
    const float* s2b  = (const float*)d_in[11];
    const float* clsW = (const float*)d_in[12];
    const float* clsb = (const float*)d_in[13];
    float* out = (float*)d_out;
    const int* src = ei;            // edge_index[0]
    const int* dst = ei + N_EDGES;  // edge_index[1]

    // ---- workspace layout (all fully rewritten each call; no stale reads) ----
    float* ws  = (float*)d_ws;
    float* A   = ws;                                  // N*256 (h1, then h3)
    float* C   = A + (size_t)N_NODES * 256;           // N*128 (gat h; later sage2 mean)
    float* D   = C + (size_t)N_NODES * 128;           // N*128 (sage1 mean(20); later gat out/h2)
    float* as_ = D + (size_t)N_NODES * 128;           // N*4
    float* ad_ = as_ + N_NODES * 4;                   // N*4
    int* deg     = (int*)(ad_ + N_NODES * 4);         // N
    int* fill    = deg + N_NODES;                     // N
    int* rowptr  = fill + N_NODES;                    // N+1
    int* csr_src = rowptr + N_NODES + 1;              // E

    const int MB = (N_NODES + 127) / 128;             // 391 row-blocks

    // ---- CSR build ----
    hipMemsetAsync(deg, 0, N_NODES * sizeof(int), stream);
    hipMemsetAsync(fill, 0, N_NODES * sizeof(int), stream);
    hist_k<<<(N_EDGES + TPB - 1) / TPB, TPB, 0, stream>>>(dst, deg);
    scan_k<<<1, 1024, 0, stream>>>(deg, rowptr);
    fill_k<<<(N_EDGES + TPB - 1) / TPB, TPB, 0, stream>>>(src, dst, rowptr, fill, csr_src);

    // ---- SAGE1:  A = relu([mean(x) | x] @ [Wl ; Wr] + b),  K = 20+20 ----
    gather_mean<20, 64><<<N_NODES, 64, 0, stream>>>(rowptr, csr_src, x, D);
    gemm_f32<1><<<dim3(4, MB), 256, 0, stream>>>(D, 20, x, 20, s1Wl, s1Wr, s1b, A, 256);

    // ---- GAT:  C = A @ gW,  K = 256 ----
    gemm_f32<0><<<dim3(2, MB), 256, 0, stream>>>(A, 256, nullptr, 0, gW, nullptr,
                                                 nullptr, C, 128);
    att_scores<<<(N_NODES * 4 + TPB - 1) / TPB, TPB, 0, stream>>>(C, gas, gad, as_, ad_);
    gat_gather4<<<N_NODES / 8, 256, 0, stream>>>(rowptr, csr_src, (const float4*)C,
                                                 as_, ad_, gb, (float4*)D);

    // ---- SAGE2:  A = relu([mean(D) | D] @ [Wl ; Wr] + b),  K = 128+128 ----
    gather_mean4<<<N_NODES / 8, 256, 0, stream>>>(rowptr, csr_src, (const float4*)D,
                                                  (float4*)C);
    gemm_f32<1><<<dim3(4, MB), 256, 0, stream>>>(C, 128, D, 128, s2Wl, s2Wr, s2b, A, 256);

    // ---- classifier ----
    cls_k<<<(N_NODES + TPB - 1) / TPB, TPB, 0, stream>>>(A, clsW, clsb, out);
}

// Round 9
// 738.663 us; speedup vs baseline: 6.0738x; 6.0738x over previous
//
#include <hip/hip_runtime.h>
#include <math.h>

#define N_NODES 50000
#define N_EDGES 800000
#define TPB 256

// ---------------- register-blocked f32 GEMM, float4-staged + pipelined ----------------
// out[M,NO] = act( [A1 | A2] @ [W1 ; W2] + bias ),  K = K1 + K2.
// REQUIRES: K1 % 4 == 0, K2 % 4 == 0 (float4 tiles never straddle the concat seam).
// BM=128, BN=64, BK=32, 256 threads, 8x4 micro-tile (acc = 32 VGPR).
// Staging: 4 float4 A-loads + 2 float4 W-loads per thread per K-tile, issued for
// tile t+1 before computing tile t (HBM latency hides under the 2048-cyc FMA phase).
// LDS: sA[32][132] (stride 132: column reads 2-way alias = free; 16B-aligned rows),
//      sB[32][68]. No launch_bounds clamp: round-8's (256,4) forced spills -> 8 GB
//      of scratch HBM traffic. Natural allocation ~100 VGPR -> 4-5 waves/SIMD.
template<int ACT>
__global__ __launch_bounds__(256) void gemm_f32(
    const float* __restrict__ A1, int K1, const float* __restrict__ A2, int K2,
    const float* __restrict__ W1, const float* __restrict__ W2,
    const float* __restrict__ bias, float* __restrict__ out, int NO) {
    constexpr int BK = 32;
    __shared__ float sA[BK][132];
    __shared__ float sB[BK][68];
    const int K = K1 + K2;
    const int T = (K + BK - 1) / BK;
    const int tid = threadIdx.x;
    const int tm = tid & 15, tn = tid >> 4;      // 16 x 16 thread grid
    const int row0 = blockIdx.y * 128;
    const int col0 = blockIdx.x * 64;
    float4 vA[4], vB[2];
    float acc[8][4] = {};

#define LOAD_TILE(t)                                                          \
    {                                                                         \
        _Pragma("unroll")                                                     \
        for (int j = 0; j < 4; ++j) {                                         \
            int e = tid + j * 256;           /* 1024 float4 slots: A tile */  \
            int kg = (t) * BK + (e & 7) * 4; /* 8 float4 per 32-k row */      \
            int mg = row0 + (e >> 3);                                         \
            float4 v = {0.f, 0.f, 0.f, 0.f};                                  \
            if (mg < N_NODES) {                                               \
                if (kg < K1)      v = *(const float4*)&A1[(size_t)mg * K1 + kg];        \
                else if (kg < K)  v = *(const float4*)&A2[(size_t)mg * K2 + (kg - K1)]; \
            }                                                                 \
            vA[j] = v;                                                        \
        }                                                                     \
        _Pragma("unroll")                                                     \
        for (int j = 0; j < 2; ++j) {                                         \
            int e = tid + j * 256;           /* 512 float4 slots: W tile */   \
            int kg = (t) * BK + (e >> 4);    /* 16 float4 per 64-col row */   \
            int ng = col0 + (e & 15) * 4;                                     \
            float4 v = {0.f, 0.f, 0.f, 0.f};                                  \
            if (kg < K1)      v = *(const float4*)&W1[(size_t)kg * NO + ng];        \
            else if (kg < K)  v = *(const float4*)&W2[(size_t)(kg - K1) * NO + ng]; \
            vB[j] = v;                                                        \
        }                                                                     \
    }

#define STORE_TILE()                                                          \
    {                                                                         \
        _Pragma("unroll")                                                     \
        for (int j = 0; j < 4; ++j) {                                         \
            int e = tid + j * 256;                                            \
            int kk0 = (e & 7) * 4, m = e >> 3;                                \
            sA[kk0 + 0][m] = vA[j].x;                                         \
            sA[kk0 + 1][m] = vA[j].y;                                         \
            sA[kk0 + 2][m] = vA[j].z;                                         \
            sA[kk0 + 3][m] = vA[j].w;                                         \
        }                                                                     \
        _Pragma("unroll")                                                     \
        for (int j = 0; j < 2; ++j) {                                         \
            int e = tid + j * 256;                                            \
            *(float4*)&sB[e >> 4][(e & 15) * 4] = vB[j];                      \
        }                                                                     \
    }

    LOAD_TILE(0);
    STORE_TILE();
    __syncthreads();

    for (int t = 0; t < T; ++t) {
        if (t + 1 < T) LOAD_TILE(t + 1);   // in flight during compute
#pragma unroll
        for (int kk = 0; kk < BK; ++kk) {
            float4 a0 = *(const float4*)&sA[kk][tm * 4];
            float4 a1 = *(const float4*)&sA[kk][64 + tm * 4];
            float4 b0 = *(const float4*)&sB[kk][tn * 4];
            float a[8] = {a0.x, a0.y, a0.z, a0.w, a1.x, a1.y, a1.z, a1.w};
            float b[4] = {b0.x, b0.y, b0.z, b0.w};
#pragma unroll
            for (int i = 0; i < 8; ++i)
#pragma unroll
                for (int j2 = 0; j2 < 4; ++j2)
                    acc[i][j2] = fmaf(a[i], b[j2], acc[i][j2]);
        }
        __syncthreads();
        if (t + 1 < T) {
            STORE_TILE();
            __syncthreads();
        }
    }

    const int ng = col0 + tn * 4;
    float4 bb = {0.f, 0.f, 0.f, 0.f};
    if (bias) bb = *(const float4*)&bias[ng];
#pragma unroll
    for (int i = 0; i < 8; ++i) {
        int mg = row0 + ((i < 4) ? (tm * 4 + i) : (64 + tm * 4 + (i - 4)));
        if (mg >= N_NODES) continue;
        float4 v;
        v.x = acc[i][0] + bb.x;
        v.y = acc[i][1] + bb.y;
        v.z = acc[i][2] + bb.z;
        v.w = acc[i][3] + bb.w;
        if (ACT) {
            v.x = fmaxf(v.x, 0.f); v.y = fmaxf(v.y, 0.f);
            v.z = fmaxf(v.z, 0.f); v.w = fmaxf(v.w, 0.f);
        }
        *(float4*)&out[(size_t)mg * NO + ng] = v;
    }
#undef LOAD_TILE
#undef STORE_TILE
}

// ---------------- CSR construction ----------------
__global__ void hist_k(const int* __restrict__ dst, int* __restrict__ deg) {
    int e = blockIdx.x * TPB + threadIdx.x;
    if (e < N_EDGES) atomicAdd(&deg[dst[e]], 1);
}

// single-block exclusive scan over deg -> rowptr (N_NODES+1 entries)
__global__ void scan_k(const int* __restrict__ deg, int* __restrict__ rowptr) {
    __shared__ int part[1024];
    const int tid = threadIdx.x;                     // 1024 threads
    const int CH = (N_NODES + 1023) / 1024;          // 49
    const int base = tid * CH;
    int s = 0;
    for (int i = 0; i < CH; ++i) {
        int idx = base + i;
        if (idx < N_NODES) s += deg[idx];
    }
    part[tid] = s;
    __syncthreads();
    for (int off = 1; off < 1024; off <<= 1) {
        int v = (tid >= off) ? part[tid - off] : 0;
        __syncthreads();
        part[tid] += v;
        __syncthreads();
    }
    int run = (tid == 0) ? 0 : part[tid - 1];
    for (int i = 0; i < CH; ++i) {
        int idx = base + i;
        if (idx < N_NODES) {
            rowptr[idx] = run;
            run += deg[idx];
        }
    }
    if (tid == 1023) rowptr[N_NODES] = run;
}

__global__ void fill_k(const int* __restrict__ src, const int* __restrict__ dst,
                       const int* __restrict__ rowptr, int* __restrict__ fill,
                       int* __restrict__ csr_src) {
    int e = blockIdx.x * TPB + threadIdx.x;
    if (e >= N_EDGES) return;
    int d = dst[e];
    int pos = rowptr[d] + atomicAdd(&fill[d], 1);
    csr_src[pos] = src[e];
}

// ---------------- gather aggregations (no scatter atomics) ----------------
// scalar version (small F, SAGE1's F=20)
template<int F, int BLK>
__global__ void gather_mean(const int* __restrict__ rowptr, const int* __restrict__ csr_src,
                            const float* __restrict__ feat, float* __restrict__ out) {
    int n = blockIdx.x;
    int c = threadIdx.x;
    if (c >= F) return;
    int e0 = rowptr[n], e1 = rowptr[n + 1];
    float acc = 0.f;
    for (int e = e0; e < e1; ++e)
        acc += feat[(size_t)csr_src[e] * F + c];
    out[(size_t)n * F + c] = acc / fmaxf((float)(e1 - e0), 1.0f);
}

// float4 version for F=128: 32 lanes/node, 8 nodes per 256-thread block
__global__ void gather_mean4(const int* __restrict__ rowptr, const int* __restrict__ csr_src,
                             const float4* __restrict__ feat4, float4* __restrict__ out4) {
    int tid = threadIdx.x;
    int n = blockIdx.x * 8 + (tid >> 5);
    int c = tid & 31;
    int e0 = rowptr[n], e1 = rowptr[n + 1];
    float4 acc = {0.f, 0.f, 0.f, 0.f};
    for (int e = e0; e < e1; ++e) {
        float4 v = feat4[(size_t)csr_src[e] * 32 + c];
        acc.x += v.x; acc.y += v.y; acc.z += v.z; acc.w += v.w;
    }
    float inv = 1.0f / fmaxf((float)(e1 - e0), 1.0f);
    acc.x *= inv; acc.y *= inv; acc.z *= inv; acc.w *= inv;
    out4[(size_t)n * 32 + c] = acc;
}

// per-(node,head) attention scores
__global__ void att_scores(const float* __restrict__ h, const float* __restrict__ att_src,
                           const float* __restrict__ att_dst, float* __restrict__ as_,
                           float* __restrict__ ad_) {
    int idx = blockIdx.x * TPB + threadIdx.x;
    if (idx >= N_NODES * 4) return;
    int n = idx >> 2, hd = idx & 3;
    const float* row = h + (size_t)n * 128 + hd * 32;
    float sa = 0.f, sd = 0.f;
    for (int c = 0; c < 32; ++c) {
        float v = row[c];
        sa = fmaf(v, att_src[hd * 32 + c], sa);
        sd = fmaf(v, att_dst[hd * 32 + c], sd);
    }
    as_[idx] = sa;
    ad_[idx] = sd;
}

// fused GAT aggregation, float4: online softmax + weighted gather + ELU
// 32 lanes/node (4 heads x 8 float4-lanes), 8 nodes per 256-thread block
__global__ void gat_gather4(const int* __restrict__ rowptr, const int* __restrict__ csr_src,
                            const float4* __restrict__ h4, const float* __restrict__ as_,
                            const float* __restrict__ ad_, const float* __restrict__ gb,
                            float4* __restrict__ out4) {
    int tid = threadIdx.x;
    int n = blockIdx.x * 8 + (tid >> 5);
    int c = tid & 31;              // float4 index within row; head = c>>3
    int hd = c >> 3;
    int e0 = rowptr[n], e1 = rowptr[n + 1];
    float ad = ad_[n * 4 + hd];
    float m = -INFINITY, s = 0.f;
    float4 acc = {0.f, 0.f, 0.f, 0.f};
    for (int e = e0; e < e1; ++e) {
        int sn = csr_src[e];
        float a = as_[sn * 4 + hd] + ad;
        a = a >= 0.f ? a : 0.2f * a;              // leaky_relu 0.2
        if (a > m) {                               // online softmax rescale
            float sc = __expf(m - a);
            s *= sc; acc.x *= sc; acc.y *= sc; acc.z *= sc; acc.w *= sc;
            m = a;
        }
        float ex = __expf(a - m);
        s += ex;
        float4 v = h4[(size_t)sn * 32 + c];
        acc.x = fmaf(v.x, ex, acc.x); acc.y = fmaf(v.y, ex, acc.y);
        acc.z = fmaf(v.z, ex, acc.z); acc.w = fmaf(v.w, ex, acc.w);
    }
    float inv = 1.0f / (s + 1e-16f);
    float4 r;
    r.x = acc.x * inv + gb[c * 4 + 0];
    r.y = acc.y * inv + gb[c * 4 + 1];
    r.z = acc.z * inv + gb[c * 4 + 2];
    r.w = acc.w * inv + gb[c * 4 + 3];
    r.x = r.x > 0.f ? r.x : expm1f(r.x);
    r.y = r.y > 0.f ? r.y : expm1f(r.y);
    r.z = r.z > 0.f ? r.z : expm1f(r.z);
    r.w = r.w > 0.f ? r.w : expm1f(r.w);
    out4[(size_t)n * 32 + c] = r;
}

// classifier: [N,256] @ [256,5] + b
__global__ void cls_k(const float* __restrict__ h, const float* __restrict__ W,
                      const float* __restrict__ b, float* __restrict__ out) {
    __shared__ float sW[256 * 5];
    for (int i = threadIdx.x; i < 1280; i += TPB) sW[i] = W[i];
    __syncthreads();
    int n = blockIdx.x * TPB + threadIdx.x;
    if (n >= N_NODES) return;
    const float4* row = (const float4*)(h + (size_t)n * 256);
    float acc[5] = {0.f, 0.f, 0.f, 0.f, 0.f};
    for (int k4 = 0; k4 < 64; ++k4) {
        float4 v = row[k4];
        const float* w = &sW[k4 * 4 * 5];
#pragma unroll
        for (int c = 0; c < 5; ++c) acc[c] = fmaf(v.x, w[c], acc[c]);
#pragma unroll
        for (int c = 0; c < 5; ++c) acc[c] = fmaf(v.y, w[5 + c], acc[c]);
#pragma unroll
        for (int c = 0; c < 5; ++c) acc[c] = fmaf(v.z, w[10 + c], acc[c]);
#pragma unroll
        for (int c = 0; c < 5; ++c) acc[c] = fmaf(v.w, w[15 + c], acc[c]);
    }
#pragma unroll
    for (int c = 0; c < 5; ++c) out[(size_t)n * 5 + c] = acc[c] + b[c];
}

extern "C" void kernel_launch(void* const* d_in, const int* in_sizes, int n_in,
                              void* d_out, int out_size, void* d_ws, size_t ws_size,
                              hipStream_t stream) {
    const float* x    = (const float*)d_in[0];
    const int*   ei   = (const int*)d_in[1];
    const float* s1Wl = (const float*)d_in[2];
    const float* s1Wr = (const float*)d_in[3];
    const float* s1b  = (const float*)d_in[4];
    const float* gW   = (const float*)d_in[5];
    const float* gas  = (const float*)d_in[6];
    const float* gad  = (const float*)d_in[7];
    const float* gb   = (const float*)d_in[8];
    const float* s2Wl = (const float*)d_in[9];
    const float* s2Wr = (const float*)d_in[10];
    const float* s2b  = (const float*)d_in[11];
    const float* clsW = (const float*)d_in[12];
    const float* clsb = (const float*)d_in[13];
    float* out = (float*)d_out;
    const int* src = ei;            // edge_index[0]
    const int* dst = ei + N_EDGES;  // edge_index[1]

    // ---- workspace layout (all fully rewritten each call; no stale reads) ----
    float* ws  = (float*)d_ws;
    float* A   = ws;                                  // N*256 (h1, then h3)
    float* C   = A + (size_t)N_NODES * 256;           // N*128 (gat h; later sage2 mean)
    float* D   = C + (size_t)N_NODES * 128;           // N*128 (sage1 mean(20); later gat out/h2)
    float* as_ = D + (size_t)N_NODES * 128;           // N*4
    float* ad_ = as_ + N_NODES * 4;                   // N*4
    int* deg     = (int*)(ad_ + N_NODES * 4);         // N
    int* fill    = deg + N_NODES;                     // N
    int* rowptr  = fill + N_NODES;                    // N+1
    int* csr_src = rowptr + N_NODES + 1;              // E

    const int MB = (N_NODES + 127) / 128;             // 391 row-blocks

    // ---- CSR build ----
    hipMemsetAsync(deg, 0, N_NODES * sizeof(int), stream);
    hipMemsetAsync(fill, 0, N_NODES * sizeof(int), stream);
    hist_k<<<(N_EDGES + TPB - 1) / TPB, TPB, 0, stream>>>(dst, deg);
    scan_k<<<1, 1024, 0, stream>>>(deg, rowptr);
    fill_k<<<(N_EDGES + TPB - 1) / TPB, TPB, 0, stream>>>(src, dst, rowptr, fill, csr_src);

    // ---- SAGE1:  A = relu([mean(x) | x] @ [Wl ; Wr] + b),  K = 20+20 ----
    gather_mean<20, 64><<<N_NODES, 64, 0, stream>>>(rowptr, csr_src, x, D);
    gemm_f32<1><<<dim3(4, MB), 256, 0, stream>>>(D, 20, x, 20, s1Wl, s1Wr, s1b, A, 256);

    // ---- GAT:  C = A @ gW,  K = 256 ----
    gemm_f32<0><<<dim3(2, MB), 256, 0, stream>>>(A, 256, nullptr, 0, gW, nullptr,
                                                 nullptr, C, 128);
    att_scores<<<(N_NODES * 4 + TPB - 1) / TPB, TPB, 0, stream>>>(C, gas, gad, as_, ad_);
    gat_gather4<<<N_NODES / 8, 256, 0, stream>>>(rowptr, csr_src, (const float4*)C,
                                                 as_, ad_, gb, (float4*)D);

    // ---- SAGE2:  A = relu([mean(D) | D] @ [Wl ; Wr] + b),  K = 128+128 ----
    gather_mean4<<<N_NODES / 8, 256, 0, stream>>>(rowptr, csr_src, (const float4*)D,
                                                  (float4*)C);
    gemm_f32<1><<<dim3(4, MB), 256, 0, stream>>>(C, 128, D, 128, s2Wl, s2Wr, s2b, A, 256);

    // ---- classifier ----
    cls_k<<<(N_NODES + TPB - 1) / TPB, TPB, 0, stream>>>(A, clsW, clsb, out);
}